// Round 8
// baseline (267.239 us; speedup 1.0000x reference)
//
#include <hip/hip_runtime.h>

#define WIN      2048
#define HOP      512
#define NFRAMES  16384
#define NBINS    1025      // WIN/2 + 1
#define FPB      8         // frames per block
#define TPB      512       // two 256-thread pipelines per block

// ---------------------------------------------------------------------------
// init: synthesis window rs[j] = (hamming/sqrt(4094)) / env, folded with the
// 1/1024 normalization of the half-size complex IFFT.
// ---------------------------------------------------------------------------
__global__ void init_rs_kernel(float* __restrict__ rs) {
    int i = blockIdx.x * blockDim.x + threadIdx.x;
    if (i >= WIN) return;
    const float inv2047 = 1.0f / 2047.0f;
    const float scale   = rsqrtf(4094.0f);
    float sw = (0.54f - 0.46f * cospif(2.0f * (float)i * inv2047)) * scale;
    int   m0 = i & 511;
    float env = 0.0f;
    #pragma unroll
    for (int r = 0; r < 4; ++r) {
        int   m = m0 + 512 * r;
        float h = (0.54f - 0.46f * cospif(2.0f * (float)m * inv2047)) * scale;
        env += h * h;
    }
    rs[i] = sw / env * (1.0f / 1024.0f);
}

__device__ __forceinline__ int pidx(int a) { return a + (a >> 3); }
__device__ __forceinline__ float2 cmul(float2 a, float2 b) {
    return make_float2(a.x * b.x - a.y * b.y, a.x * b.y + a.y * b.x);
}

// ---------------------------------------------------------------------------
// 512 threads = two 256-thread pipelines (half = tid>>8). Pair iteration pi
// processes frames 2pi (half 0) and 2pi+1 (half 1) in lockstep, sharing 5
// __syncthreads per pair (2.5 per frame):
//  pack+s0 : mirror bins loaded directly from global (no LDS spectrum stage),
//            Hermitian half-size pack fused with radix-4 stage 0  -> bufA
//  s1..s3  : radix-4 Stockham, reg-hoisted twiddles (ping-pong)
//  s4+OLA  : last stage (twiddle=1) + fftshift + window -> shared 8-chunk
//            ring accumulator via workgroup-scope LDS float atomics
//  flush   : chunks 2pi, 2pi+1 now complete -> store/atomic to global, zero
// Ring slots alias mod 8; liveness spans 5 chunks -> safe. Chunks 0-2 and
// 8-10 are block seams (atomicAdd), 3-7 interior (plain store).
// ---------------------------------------------------------------------------
__global__ __launch_bounds__(TPB, 6) void istft_kernel(
        const float* __restrict__ mag, const float* __restrict__ ph,
        const float* __restrict__ rs, float* __restrict__ out, int out_size) {
    __shared__ float2 bufA[2][1152];     // 18432 B
    __shared__ float2 bufB[2][1152];     // 18432 B
    __shared__ float2 ring[2048];        // 16384 B: 8 chunks x 256 float2

    const int tid  = threadIdx.x;
    const int half = tid >> 8;
    const int t    = tid & 255;
    float2* bA = bufA[half];
    float2* bB = bufB[half];
    float*  rf = (float*)ring;
    const int frame0 = blockIdx.x * FPB;

    // ---- frame-invariant per-thread constants (function of t only) ----
    float2 wpk;                                    // e^{2pi i t/2048}
    sincospif((float)t * (1.0f / 1024.0f), &wpk.y, &wpk.x);
    float2 wst[4], w2st[4];
    wst[0] = cmul(wpk, wpk);                       // e^{2pi i t/1024}
    sincospif((float)(t & ~3)  * (1.0f / 512.0f), &wst[1].y, &wst[1].x);
    sincospif((float)(t & ~15) * (1.0f / 512.0f), &wst[2].y, &wst[2].x);
    sincospif((float)(t & ~63) * (1.0f / 512.0f), &wst[3].y, &wst[3].x);
    #pragma unroll
    for (int q = 0; q < 4; ++q) w2st[q] = cmul(wst[q], wst[q]);

    const float2* rs2 = (const float2*)rs;
    const float2 r0 = rs2[t], r1 = rs2[t + 256],
                 r2 = rs2[t + 512], r3 = rs2[t + 768];
    const float RT = 0.70710678118654752f;         // sqrt(2)/2

    for (int i = tid; i < 2048; i += TPB) ring[i] = make_float2(0.0f, 0.0f);
    // (pack barrier of pair 0 orders zeroing before first OLA)

    for (int pi = 0; pi < 4; ++pi) {
        const int fi = 2 * pi + half;
        const float* magf = mag + (size_t)(frame0 + fi) * NBINS;
        const float* phf  = ph  + (size_t)(frame0 + fi) * NBINS;

        // ---- pack (mirrors from global) + stage0 -> bufA ----
        {
            float2 z[4];
            #pragma unroll
            for (int j = 0; j < 4; ++j) {
                const int k  = t + 256 * j;
                const int mk = 1024 - k;
                float mgk = magf[k],  phk = phf[k];
                float mgm = magf[mk], phm = phf[mk];
                float s, c;
                __sincosf(phk, &s, &c);
                float2 Xk = make_float2(mgk * c, mgk * s);
                __sincosf(phm, &s, &c);
                float2 Xm = make_float2(mgm * c, mgm * s);
                if (k == 0) { Xk.y = 0.0f; Xm.y = 0.0f; }   // DC/Nyquist imag
                float2 wj;                         // e^{2pi i k/2048}
                if      (j == 0) wj = wpk;
                else if (j == 1) wj = make_float2(RT * (wpk.x - wpk.y), RT * (wpk.x + wpk.y));
                else if (j == 2) wj = make_float2(-wpk.y, wpk.x);
                else             wj = make_float2(-RT * (wpk.x + wpk.y), RT * (wpk.x - wpk.y));
                float Er = 0.5f * (Xk.x + Xm.x), Ei = 0.5f * (Xk.y - Xm.y);
                float Tr = Xm.x - Xk.x,          Ti = -Xm.y - Xk.y;
                float Or = 0.5f * (wj.x * Ti + wj.y * Tr);
                float Oi = 0.5f * (wj.y * Ti - wj.x * Tr);
                z[j] = make_float2(Er + Or, Ei + Oi);
            }
            float2 w = wst[0], w2 = w2st[0];
            float2 u0 = make_float2(z[0].x + z[2].x, z[0].y + z[2].y);
            float  ar = z[0].x - z[2].x, ai = z[0].y - z[2].y;
            float2 u1 = make_float2(ar * w.x - ai * w.y, ar * w.y + ai * w.x);
            float2 u2 = make_float2(z[1].x + z[3].x, z[1].y + z[3].y);
            float  br = z[1].x - z[3].x, bi = z[1].y - z[3].y;
            float2 u3 = make_float2(-br * w.y - bi * w.x, br * w.x - bi * w.y);
            const int base = 4 * t;                // t + 3*G, G=t, s4=1
            bA[pidx(base)]     = make_float2(u0.x + u2.x, u0.y + u2.y);
            bA[pidx(base + 1)] = make_float2(u1.x + u3.x, u1.y + u3.y);
            float dr = u0.x - u2.x, di = u0.y - u2.y;
            bA[pidx(base + 2)] = make_float2(dr * w2.x - di * w2.y, dr * w2.y + di * w2.x);
            float er = u1.x - u3.x, ei = u1.y - u3.y;
            bA[pidx(base + 3)] = make_float2(er * w2.x - ei * w2.y, er * w2.y + ei * w2.x);
        }
        __syncthreads();

        // ---- stages 1..3 (bA->bB->bA->bB) ----
        {
            float2* src = bA;
            float2* dst = bB;
            #pragma unroll
            for (int st = 1; st < 4; ++st) {
                const int s4 = 1 << (2 * st);
                const int G  = t & ~(s4 - 1);
                float2 x0 = src[pidx(t)];
                float2 x1 = src[pidx(t + 256)];
                float2 x2 = src[pidx(t + 512)];
                float2 x3 = src[pidx(t + 768)];
                float2 w = wst[st], w2 = w2st[st];
                float2 u0 = make_float2(x0.x + x2.x, x0.y + x2.y);
                float  ar = x0.x - x2.x, ai = x0.y - x2.y;
                float2 u1 = make_float2(ar * w.x - ai * w.y, ar * w.y + ai * w.x);
                float2 u2 = make_float2(x1.x + x3.x, x1.y + x3.y);
                float  br = x1.x - x3.x, bi = x1.y - x3.y;
                float2 u3 = make_float2(-br * w.y - bi * w.x, br * w.x - bi * w.y);
                const int base = t + 3 * G;
                dst[pidx(base)]          = make_float2(u0.x + u2.x, u0.y + u2.y);
                dst[pidx(base + s4)]     = make_float2(u1.x + u3.x, u1.y + u3.y);
                float dr = u0.x - u2.x, di = u0.y - u2.y;
                dst[pidx(base + 2 * s4)] = make_float2(dr * w2.x - di * w2.y, dr * w2.y + di * w2.x);
                float er = u1.x - u3.x, ei = u1.y - u3.y;
                dst[pidx(base + 3 * s4)] = make_float2(er * w2.x - ei * w2.y, er * w2.y + ei * w2.x);
                __syncthreads();
                float2* tmp = src; src = dst; dst = tmp;
            }
        }
        // data now in bB

        // ---- stage4 (w=1) + fftshift + window + LDS-atomic OLA into ring ----
        {
            float2 x0 = bB[pidx(t)];
            float2 x1 = bB[pidx(t + 256)];
            float2 x2 = bB[pidx(t + 512)];
            float2 x3 = bB[pidx(t + 768)];
            float2 u0 = make_float2(x0.x + x2.x, x0.y + x2.y);
            float2 u1 = make_float2(x0.x - x2.x, x0.y - x2.y);
            float2 u2 = make_float2(x1.x + x3.x, x1.y + x3.y);
            float2 u3 = make_float2(-(x1.y - x3.y), x1.x - x3.x);   // i*(x1-x3)
            const int A0 = fi * 256;
            float2 y; int idx;
            // n=t       -> t2=t+512 (fftshift), window r2
            y = make_float2(u0.x + u2.x, u0.y + u2.y);
            idx = (A0 + t + 512) & 2047;
            __hip_atomic_fetch_add(&rf[2 * idx],     y.x * r2.x, __ATOMIC_RELAXED, __HIP_MEMORY_SCOPE_WORKGROUP);
            __hip_atomic_fetch_add(&rf[2 * idx + 1], y.y * r2.y, __ATOMIC_RELAXED, __HIP_MEMORY_SCOPE_WORKGROUP);
            // n=t+256   -> t2=t+768, window r3
            y = make_float2(u1.x + u3.x, u1.y + u3.y);
            idx = (A0 + t + 768) & 2047;
            __hip_atomic_fetch_add(&rf[2 * idx],     y.x * r3.x, __ATOMIC_RELAXED, __HIP_MEMORY_SCOPE_WORKGROUP);
            __hip_atomic_fetch_add(&rf[2 * idx + 1], y.y * r3.y, __ATOMIC_RELAXED, __HIP_MEMORY_SCOPE_WORKGROUP);
            // n=t+512   -> t2=t, window r0
            y = make_float2(u0.x - u2.x, u0.y - u2.y);
            idx = (A0 + t) & 2047;
            __hip_atomic_fetch_add(&rf[2 * idx],     y.x * r0.x, __ATOMIC_RELAXED, __HIP_MEMORY_SCOPE_WORKGROUP);
            __hip_atomic_fetch_add(&rf[2 * idx + 1], y.y * r0.y, __ATOMIC_RELAXED, __HIP_MEMORY_SCOPE_WORKGROUP);
            // n=t+768   -> t2=t+256, window r1
            y = make_float2(u1.x - u3.x, u1.y - u3.y);
            idx = (A0 + t + 256) & 2047;
            __hip_atomic_fetch_add(&rf[2 * idx],     y.x * r1.x, __ATOMIC_RELAXED, __HIP_MEMORY_SCOPE_WORKGROUP);
            __hip_atomic_fetch_add(&rf[2 * idx + 1], y.y * r1.y, __ATOMIC_RELAXED, __HIP_MEMORY_SCOPE_WORKGROUP);
        }
        __syncthreads();

        // ---- flush chunks 2pi (half 0) and 2pi+1 (half 1): complete ----
        {
            const int lc   = 2 * pi + half;
            const int slot = (lc * 256 + t) & 2047;
            float2 v = ring[slot];
            ring[slot] = make_float2(0.0f, 0.0f);   // thread-private RMW
            long p = (long)(frame0 + lc) * HOP + 2 * t - 1536;
            if (lc >= 3) {                           // interior: plain store
                if (p >= 0 && p < out_size)         out[p]     = v.x;
                if (p + 1 >= 0 && p + 1 < out_size) out[p + 1] = v.y;
            } else {                                 // seam: atomic
                if (p >= 0 && p < out_size)         atomicAdd(out + p,     v.x);
                if (p + 1 >= 0 && p + 1 < out_size) atomicAdd(out + p + 1, v.y);
            }
        }
        // no barrier: next ring access (pair pi+1 OLA) is 5 barriers away
    }

    // ---- tail: chunks 8,9,10 (slots 0,1,2) are partial -> atomic ----
    for (int x = tid; x < 768; x += TPB) {
        const int lc   = 8 + (x >> 8);
        const int tt   = x & 255;
        const int slot = (lc * 256 + tt) & 2047;
        float2 v = ring[slot];
        long p = (long)(frame0 + lc) * HOP + 2 * tt - 1536;
        if (p >= 0 && p < out_size)         atomicAdd(out + p,     v.x);
        if (p + 1 >= 0 && p + 1 < out_size) atomicAdd(out + p + 1, v.y);
    }
}

extern "C" void kernel_launch(void* const* d_in, const int* in_sizes, int n_in,
                              void* d_out, int out_size, void* d_ws, size_t ws_size,
                              hipStream_t stream) {
    const float* mag = (const float*)d_in[0];
    const float* ph  = (const float*)d_in[1];
    float* out = (float*)d_out;
    float* rs  = (float*)d_ws;

    hipMemsetAsync(d_out, 0, (size_t)out_size * sizeof(float), stream);
    init_rs_kernel<<<(WIN + 255) / 256, 256, 0, stream>>>(rs);
    istft_kernel<<<NFRAMES / FPB, TPB, 0, stream>>>(mag, ph, rs, out, out_size);
}

// Round 9
// 104.102 us; speedup vs baseline: 2.5671x; 2.5671x over previous
//
#include <hip/hip_runtime.h>

#define WIN      2048
#define HOP      512
#define NFRAMES  16384
#define NBINS    1025      // WIN/2 + 1
#define FPB      8         // frames per block (processed as 4 pairs)

// ---------------------------------------------------------------------------
// init: synthesis window rs[j] = (hamming/sqrt(4094)) / env, folded with the
// 1/1024 normalization of the half-size complex IFFT.
// ---------------------------------------------------------------------------
__global__ void init_rs_kernel(float* __restrict__ rs) {
    int i = blockIdx.x * blockDim.x + threadIdx.x;
    if (i >= WIN) return;
    const float inv2047 = 1.0f / 2047.0f;
    const float scale   = rsqrtf(4094.0f);
    float sw = (0.54f - 0.46f * cospif(2.0f * (float)i * inv2047)) * scale;
    int   m0 = i & 511;
    float env = 0.0f;
    #pragma unroll
    for (int r = 0; r < 4; ++r) {
        int   m = m0 + 512 * r;
        float h = (0.54f - 0.46f * cospif(2.0f * (float)m * inv2047)) * scale;
        env += h * h;
    }
    rs[i] = sw / env * (1.0f / 1024.0f);
}

__device__ __forceinline__ int pidx(int a) { return a + (a >> 3); }
__device__ __forceinline__ float2 cmul(float2 a, float2 b) {
    return make_float2(a.x * b.x - a.y * b.y, a.x * b.y + a.y * b.x);
}

// ---------------------------------------------------------------------------
// 256 threads per block, FPB=8 frames processed as 4 PAIRS. Each phase handles
// both frames of the pair (static [2] unroll) -> 6 barriers per pair = 3 per
// frame, and two independent dep-chains per thread (ILP).
//  A     : spectra of both frames -> bufB[h] (coalesced forward reads only)
//  pack+s0: Hermitian half-size pack fused with radix-4 stage0 -> bufA[h]
//  s1..s3 : radix-4 Stockham, reg-hoisted twiddles (ping-pong per h)
//  s4+OLA : last stage (twiddle=1) + fftshift + window -> 8-chunk ring acc.
//           Ring slot s is touched ONLY by thread s%256 (quadrant math) ->
//           plain RMW, no atomics, no barriers for ring traffic.
//  flush  : chunks 2pi, 2pi+1 complete -> store (interior) / atomic (seams)
// ---------------------------------------------------------------------------
__global__ __launch_bounds__(256, 4) void istft_kernel(
        const float* __restrict__ mag, const float* __restrict__ ph,
        const float* __restrict__ rs, float* __restrict__ out, int out_size) {
    __shared__ float2 bufA[2][1152];     // 18432 B
    __shared__ float2 bufB[2][1152];     // 18432 B
    __shared__ float2 ring[2048];        // 16384 B: 8 chunks x 256 float2

    const int tid    = threadIdx.x;
    const int frame0 = blockIdx.x * FPB;

    // ---- frame-invariant per-thread constants ----
    float2 wpk;                                    // e^{2pi i tid/2048}
    sincospif((float)tid * (1.0f / 1024.0f), &wpk.y, &wpk.x);
    float2 wst[4], w2st[4];
    wst[0] = cmul(wpk, wpk);                       // e^{2pi i tid/1024}
    sincospif((float)(tid & ~3)  * (1.0f / 512.0f), &wst[1].y, &wst[1].x);
    sincospif((float)(tid & ~15) * (1.0f / 512.0f), &wst[2].y, &wst[2].x);
    sincospif((float)(tid & ~63) * (1.0f / 512.0f), &wst[3].y, &wst[3].x);
    #pragma unroll
    for (int q = 0; q < 4; ++q) w2st[q] = cmul(wst[q], wst[q]);

    const float2* rs2 = (const float2*)rs;
    const float2 r0 = rs2[tid], r1 = rs2[tid + 256],
                 r2 = rs2[tid + 512], r3 = rs2[tid + 768];
    const float RT = 0.70710678118654752f;         // sqrt(2)/2

    // zero ring: slot i handled by thread i%256 (ownership invariant)
    for (int i = tid; i < 2048; i += 256) ring[i] = make_float2(0.0f, 0.0f);
    // (first pair's phase-A barrier orders zeroing before first OLA)

    for (int pi = 0; pi < 4; ++pi) {
        // ---- A: both spectra -> bufB[h] ----
        #pragma unroll
        for (int h = 0; h < 2; ++h) {
            const size_t fb = (size_t)(frame0 + 2 * pi + h) * NBINS;
            const float* magf = mag + fb;
            const float* phf  = ph  + fb;
            for (int k = tid; k < NBINS; k += 256) {
                float s, c;
                __sincosf(phf[k], &s, &c);
                float m = magf[k];
                float re = m * c, im = m * s;
                if (k == 0 || k == 1024) im = 0.0f;
                bufB[h][k] = make_float2(re, im);
            }
        }
        __syncthreads();

        // ---- pack + stage0 -> bufA[h] ----
        #pragma unroll
        for (int h = 0; h < 2; ++h) {
            float2 z[4];
            #pragma unroll
            for (int j = 0; j < 4; ++j) {
                int k = tid + j * 256;
                float2 Xk = bufB[h][k];
                float2 Xm = bufB[h][1024 - k];
                float2 wj;                         // wpk * e^{i pi j/4}
                if      (j == 0) wj = wpk;
                else if (j == 1) wj = make_float2(RT * (wpk.x - wpk.y), RT * (wpk.x + wpk.y));
                else if (j == 2) wj = make_float2(-wpk.y, wpk.x);
                else             wj = make_float2(-RT * (wpk.x + wpk.y), RT * (wpk.x - wpk.y));
                float Er = 0.5f * (Xk.x + Xm.x), Ei = 0.5f * (Xk.y - Xm.y);
                float Tr = Xm.x - Xk.x,          Ti = -Xm.y - Xk.y;
                float Or = 0.5f * (wj.x * Ti + wj.y * Tr);
                float Oi = 0.5f * (wj.y * Ti - wj.x * Tr);
                z[j] = make_float2(Er + Or, Ei + Oi);
            }
            float2 w = wst[0], w2 = w2st[0];
            float2 u0 = make_float2(z[0].x + z[2].x, z[0].y + z[2].y);
            float  ar = z[0].x - z[2].x, ai = z[0].y - z[2].y;
            float2 u1 = make_float2(ar * w.x - ai * w.y, ar * w.y + ai * w.x);
            float2 u2 = make_float2(z[1].x + z[3].x, z[1].y + z[3].y);
            float  br = z[1].x - z[3].x, bi = z[1].y - z[3].y;
            float2 u3 = make_float2(-br * w.y - bi * w.x, br * w.x - bi * w.y);
            const int base = 4 * tid;              // tid + 3*G, G=tid, s4=1
            bufA[h][pidx(base)]     = make_float2(u0.x + u2.x, u0.y + u2.y);
            bufA[h][pidx(base + 1)] = make_float2(u1.x + u3.x, u1.y + u3.y);
            float dr = u0.x - u2.x, di = u0.y - u2.y;
            bufA[h][pidx(base + 2)] = make_float2(dr * w2.x - di * w2.y, dr * w2.y + di * w2.x);
            float er = u1.x - u3.x, ei = u1.y - u3.y;
            bufA[h][pidx(base + 3)] = make_float2(er * w2.x - ei * w2.y, er * w2.y + ei * w2.x);
        }
        __syncthreads();

        // ---- stages 1..3, both frames per barrier (A->B->A->B) ----
        #pragma unroll
        for (int st = 1; st < 4; ++st) {
            const int s4 = 1 << (2 * st);
            const int G  = tid & ~(s4 - 1);
            const float2 w = wst[st], w2 = w2st[st];
            #pragma unroll
            for (int h = 0; h < 2; ++h) {
                // ping-pong: st odd reads bufA writes bufB; st even reverse
                float2* src = (st & 1) ? bufA[h] : bufB[h];
                float2* dst = (st & 1) ? bufB[h] : bufA[h];
                float2 x0 = src[pidx(tid)];
                float2 x1 = src[pidx(tid + 256)];
                float2 x2 = src[pidx(tid + 512)];
                float2 x3 = src[pidx(tid + 768)];
                float2 u0 = make_float2(x0.x + x2.x, x0.y + x2.y);
                float  ar = x0.x - x2.x, ai = x0.y - x2.y;
                float2 u1 = make_float2(ar * w.x - ai * w.y, ar * w.y + ai * w.x);
                float2 u2 = make_float2(x1.x + x3.x, x1.y + x3.y);
                float  br = x1.x - x3.x, bi = x1.y - x3.y;
                float2 u3 = make_float2(-br * w.y - bi * w.x, br * w.x - bi * w.y);
                const int base = tid + 3 * G;
                dst[pidx(base)]          = make_float2(u0.x + u2.x, u0.y + u2.y);
                dst[pidx(base + s4)]     = make_float2(u1.x + u3.x, u1.y + u3.y);
                float dr = u0.x - u2.x, di = u0.y - u2.y;
                dst[pidx(base + 2 * s4)] = make_float2(dr * w2.x - di * w2.y, dr * w2.y + di * w2.x);
                float er = u1.x - u3.x, ei = u1.y - u3.y;
                dst[pidx(base + 3 * s4)] = make_float2(er * w2.x - ei * w2.y, er * w2.y + ei * w2.x);
            }
            __syncthreads();
        }
        // data now in bufB[h]

        // ---- s4 (w=1) + fftshift + window + ring OLA (thread-owned RMW) ----
        #pragma unroll
        for (int h = 0; h < 2; ++h) {
            const int fi = 2 * pi + h;
            float2 x0 = bufB[h][pidx(tid)];
            float2 x1 = bufB[h][pidx(tid + 256)];
            float2 x2 = bufB[h][pidx(tid + 512)];
            float2 x3 = bufB[h][pidx(tid + 768)];
            float2 u0 = make_float2(x0.x + x2.x, x0.y + x2.y);
            float2 u1 = make_float2(x0.x - x2.x, x0.y - x2.y);
            float2 u2 = make_float2(x1.x + x3.x, x1.y + x3.y);
            float2 u3 = make_float2(-(x1.y - x3.y), x1.x - x3.x);   // i*(x1-x3)
            const int A0 = fi * 256;
            float2 y, a; int idx;
            // n=tid     -> t2=tid+512 (fftshift), window r2
            y = make_float2(u0.x + u2.x, u0.y + u2.y);
            idx = (A0 + tid + 512) & 2047;
            a = ring[idx]; ring[idx] = make_float2(a.x + y.x * r2.x, a.y + y.y * r2.y);
            // n=tid+256 -> t2=tid+768, window r3
            y = make_float2(u1.x + u3.x, u1.y + u3.y);
            idx = (A0 + tid + 768) & 2047;
            a = ring[idx]; ring[idx] = make_float2(a.x + y.x * r3.x, a.y + y.y * r3.y);
            // n=tid+512 -> t2=tid, window r0
            y = make_float2(u0.x - u2.x, u0.y - u2.y);
            idx = (A0 + tid) & 2047;
            a = ring[idx]; ring[idx] = make_float2(a.x + y.x * r0.x, a.y + y.y * r0.y);
            // n=tid+768 -> t2=tid+256, window r1
            y = make_float2(u1.x - u3.x, u1.y - u3.y);
            idx = (A0 + tid + 256) & 2047;
            a = ring[idx]; ring[idx] = make_float2(a.x + y.x * r1.x, a.y + y.y * r1.y);
        }

        // ---- flush chunks 2pi, 2pi+1 (complete; same-thread ordering) ----
        #pragma unroll
        for (int h = 0; h < 2; ++h) {
            const int lc   = 2 * pi + h;
            const int slot = (lc * 256 + tid) & 2047;
            float2 v = ring[slot];
            ring[slot] = make_float2(0.0f, 0.0f);
            long p = (long)(frame0 + lc) * HOP + 2 * tid - 1536;
            if (lc >= 3) {                           // interior: plain store
                if (p >= 0 && p < out_size)         out[p]     = v.x;
                if (p + 1 >= 0 && p + 1 < out_size) out[p + 1] = v.y;
            } else {                                 // seam: atomic
                if (p >= 0 && p < out_size)         atomicAdd(out + p,     v.x);
                if (p + 1 >= 0 && p + 1 < out_size) atomicAdd(out + p + 1, v.y);
            }
        }
        __syncthreads();    // bufB reads (s4) done before next pair's A writes
    }

    // ---- tail: chunks 8,9,10 partial -> atomic (thread-owned slots) ----
    #pragma unroll
    for (int lc = 8; lc <= 10; ++lc) {
        const int slot = (lc * 256 + tid) & 2047;
        float2 v = ring[slot];
        long p = (long)(frame0 + lc) * HOP + 2 * tid - 1536;
        if (p >= 0 && p < out_size)         atomicAdd(out + p,     v.x);
        if (p + 1 >= 0 && p + 1 < out_size) atomicAdd(out + p + 1, v.y);
    }
}

extern "C" void kernel_launch(void* const* d_in, const int* in_sizes, int n_in,
                              void* d_out, int out_size, void* d_ws, size_t ws_size,
                              hipStream_t stream) {
    const float* mag = (const float*)d_in[0];
    const float* ph  = (const float*)d_in[1];
    float* out = (float*)d_out;
    float* rs  = (float*)d_ws;

    hipMemsetAsync(d_out, 0, (size_t)out_size * sizeof(float), stream);
    init_rs_kernel<<<(WIN + 255) / 256, 256, 0, stream>>>(rs);
    istft_kernel<<<NFRAMES / FPB, 256, 0, stream>>>(mag, ph, rs, out, out_size);
}

// Round 10
// 69.312 us; speedup vs baseline: 3.8556x; 1.5019x over previous
//
#include <hip/hip_runtime.h>

#define WIN      2048
#define HOP      512
#define NFRAMES  16384
#define NBINS    1025      // WIN/2 + 1
#define FPB      8         // frames per block

// ---------------------------------------------------------------------------
// init: synthesis window rs[j] = (hamming/sqrt(4094)) / env, folded with the
// 1/1024 normalization of the half-size complex IFFT.
// ---------------------------------------------------------------------------
__global__ void init_rs_kernel(float* __restrict__ rs) {
    int i = blockIdx.x * blockDim.x + threadIdx.x;
    if (i >= WIN) return;
    const float inv2047 = 1.0f / 2047.0f;
    const float scale   = rsqrtf(4094.0f);
    float sw = (0.54f - 0.46f * cospif(2.0f * (float)i * inv2047)) * scale;
    int   m0 = i & 511;
    float env = 0.0f;
    #pragma unroll
    for (int r = 0; r < 4; ++r) {
        int   m = m0 + 512 * r;
        float h = (0.54f - 0.46f * cospif(2.0f * (float)m * inv2047)) * scale;
        env += h * h;
    }
    rs[i] = sw / env * (1.0f / 1024.0f);
}

__device__ __forceinline__ int pidx(int a) { return a + (a >> 3); }
__device__ __forceinline__ float2 cmul(float2 a, float2 b) {
    return make_float2(a.x * b.x - a.y * b.y, a.x * b.y + a.y * b.x);
}

// ---------------------------------------------------------------------------
// 256 threads, 8 frames, fully unrolled software pipeline (4 barriers/frame):
//  P1: issue frame fi+1 global loads (regs); pack fi (Xk from regs, mirror
//      from S[cur]) fused with radix-4 stage0 -> W1          [barrier]
//  P2: s1  W1 -> W2                                          [barrier]
//  P3: s2  W2 -> W1                                          [barrier]
//  P4: s3  W1 -> W2 ; sincos(fi+1) -> xk regs + S[nxt]       [barrier]
//  P5: s4 (twiddle=1) + fftshift + window -> 4 register accumulators
//      (thread owns intra-chunk offset 2*tid of the 4 live chunks);
//      flush chunk fi to global (plain interior / atomic seams). No barrier:
//      next W2 write is 2 barriers away.
// ---------------------------------------------------------------------------
__global__ __launch_bounds__(256, 4) void istft_kernel(
        const float* __restrict__ mag, const float* __restrict__ ph,
        const float* __restrict__ rs, float* __restrict__ out, int out_size) {
    __shared__ float2 W1[1152];          // 9216 B (pidx-padded 1024)
    __shared__ float2 W2[1152];          // 9216 B
    __shared__ float2 S[2][1026];        // 2 x 8208 B spectrum buffers

    const int tid    = threadIdx.x;
    const int frame0 = blockIdx.x * FPB;

    // ---- frame-invariant per-thread constants ----
    float2 wpk;                                    // e^{2pi i tid/2048}
    sincospif((float)tid * (1.0f / 1024.0f), &wpk.y, &wpk.x);
    float2 wst[4], w2st[4];
    wst[0] = cmul(wpk, wpk);                       // e^{2pi i tid/1024}
    sincospif((float)(tid & ~3)  * (1.0f / 512.0f), &wst[1].y, &wst[1].x);
    sincospif((float)(tid & ~15) * (1.0f / 512.0f), &wst[2].y, &wst[2].x);
    sincospif((float)(tid & ~63) * (1.0f / 512.0f), &wst[3].y, &wst[3].x);
    #pragma unroll
    for (int q = 0; q < 4; ++q) w2st[q] = cmul(wst[q], wst[q]);

    const float2* rs2 = (const float2*)rs;
    const float2 r0 = rs2[tid], r1 = rs2[tid + 256],
                 r2 = rs2[tid + 512], r3 = rs2[tid + 768];
    const float RT = 0.70710678118654752f;         // sqrt(2)/2

    float2 xk[2][4];                     // forward bins of cur/next frame
    float  mgn[4], ppn[4], nymg, nyph;   // staged loads for next frame
    float2 acc[4];                       // 4 live OLA chunks, offset 2*tid
    acc[0] = acc[1] = acc[2] = acc[3] = make_float2(0.0f, 0.0f);

    // ---- prologue: load + convert frame 0, write S[0] ----
    {
        const float* magf = mag + (size_t)frame0 * NBINS;
        const float* phf  = ph  + (size_t)frame0 * NBINS;
        #pragma unroll
        for (int j = 0; j < 4; ++j) {
            mgn[j] = magf[tid + 256 * j];
            ppn[j] = phf[tid + 256 * j];
        }
        nymg = magf[1024]; nyph = phf[1024];
        #pragma unroll
        for (int j = 0; j < 4; ++j) {
            float s, c;
            __sincosf(ppn[j], &s, &c);
            float2 X = make_float2(mgn[j] * c, mgn[j] * s);
            if (j == 0 && tid == 0) X.y = 0.0f;    // DC imag
            xk[0][j] = X;
            S[0][tid + 256 * j] = X;
        }
        if (tid == 0) {
            float s, c;
            __sincosf(nyph, &s, &c);
            S[0][1024] = make_float2(nymg * c, 0.0f);   // Nyquist imag = 0
        }
    }
    __syncthreads();

    #pragma unroll
    for (int fi = 0; fi < FPB; ++fi) {
        const int cur = fi & 1, nxt = cur ^ 1;

        // ---- P1: issue next-frame loads, then pack + s0 -> W1 ----
        if (fi < FPB - 1) {
            const float* magf = mag + (size_t)(frame0 + fi + 1) * NBINS;
            const float* phf  = ph  + (size_t)(frame0 + fi + 1) * NBINS;
            #pragma unroll
            for (int j = 0; j < 4; ++j) {
                mgn[j] = magf[tid + 256 * j];
                ppn[j] = phf[tid + 256 * j];
            }
            nymg = magf[1024]; nyph = phf[1024];
        }
        {
            float2 z[4];
            #pragma unroll
            for (int j = 0; j < 4; ++j) {
                float2 Xk = xk[cur][j];
                float2 Xm = S[cur][1024 - (tid + 256 * j)];
                float2 wj;                         // wpk * e^{i pi j/4}
                if      (j == 0) wj = wpk;
                else if (j == 1) wj = make_float2(RT * (wpk.x - wpk.y), RT * (wpk.x + wpk.y));
                else if (j == 2) wj = make_float2(-wpk.y, wpk.x);
                else             wj = make_float2(-RT * (wpk.x + wpk.y), RT * (wpk.x - wpk.y));
                float Er = 0.5f * (Xk.x + Xm.x), Ei = 0.5f * (Xk.y - Xm.y);
                float Tr = Xm.x - Xk.x,          Ti = -Xm.y - Xk.y;
                float Or = 0.5f * (wj.x * Ti + wj.y * Tr);
                float Oi = 0.5f * (wj.y * Ti - wj.x * Tr);
                z[j] = make_float2(Er + Or, Ei + Oi);
            }
            float2 w = wst[0], w2 = w2st[0];
            float2 u0 = make_float2(z[0].x + z[2].x, z[0].y + z[2].y);
            float  ar = z[0].x - z[2].x, ai = z[0].y - z[2].y;
            float2 u1 = make_float2(ar * w.x - ai * w.y, ar * w.y + ai * w.x);
            float2 u2 = make_float2(z[1].x + z[3].x, z[1].y + z[3].y);
            float  br = z[1].x - z[3].x, bi = z[1].y - z[3].y;
            float2 u3 = make_float2(-br * w.y - bi * w.x, br * w.x - bi * w.y);
            const int base = 4 * tid;              // tid + 3*G, G=tid, s4=1
            W1[pidx(base)]     = make_float2(u0.x + u2.x, u0.y + u2.y);
            W1[pidx(base + 1)] = make_float2(u1.x + u3.x, u1.y + u3.y);
            float dr = u0.x - u2.x, di = u0.y - u2.y;
            W1[pidx(base + 2)] = make_float2(dr * w2.x - di * w2.y, dr * w2.y + di * w2.x);
            float er = u1.x - u3.x, ei = u1.y - u3.y;
            W1[pidx(base + 3)] = make_float2(er * w2.x - ei * w2.y, er * w2.y + ei * w2.x);
        }
        __syncthreads();

        // ---- P2/P3/P4: stages 1..3 ----
        #pragma unroll
        for (int st = 1; st < 4; ++st) {
            float2* src = (st == 2) ? W2 : W1;     // s1:W1->W2 s2:W2->W1 s3:W1->W2
            float2* dst = (st == 2) ? W1 : W2;
            const int s4 = 1 << (2 * st);
            const int G  = tid & ~(s4 - 1);
            const float2 w = wst[st], w2 = w2st[st];
            float2 x0 = src[pidx(tid)];
            float2 x1 = src[pidx(tid + 256)];
            float2 x2 = src[pidx(tid + 512)];
            float2 x3 = src[pidx(tid + 768)];
            float2 u0 = make_float2(x0.x + x2.x, x0.y + x2.y);
            float  ar = x0.x - x2.x, ai = x0.y - x2.y;
            float2 u1 = make_float2(ar * w.x - ai * w.y, ar * w.y + ai * w.x);
            float2 u2 = make_float2(x1.x + x3.x, x1.y + x3.y);
            float  br = x1.x - x3.x, bi = x1.y - x3.y;
            float2 u3 = make_float2(-br * w.y - bi * w.x, br * w.x - bi * w.y);
            const int base = tid + 3 * G;
            dst[pidx(base)]          = make_float2(u0.x + u2.x, u0.y + u2.y);
            dst[pidx(base + s4)]     = make_float2(u1.x + u3.x, u1.y + u3.y);
            float dr = u0.x - u2.x, di = u0.y - u2.y;
            dst[pidx(base + 2 * s4)] = make_float2(dr * w2.x - di * w2.y, dr * w2.y + di * w2.x);
            float er = u1.x - u3.x, ei = u1.y - u3.y;
            dst[pidx(base + 3 * s4)] = make_float2(er * w2.x - ei * w2.y, er * w2.y + ei * w2.x);

            // fold next-frame spectrum conversion into the s3 phase
            if (st == 3 && fi < FPB - 1) {
                #pragma unroll
                for (int j = 0; j < 4; ++j) {
                    float s, c;
                    __sincosf(ppn[j], &s, &c);
                    float2 X = make_float2(mgn[j] * c, mgn[j] * s);
                    if (j == 0 && tid == 0) X.y = 0.0f;
                    xk[nxt][j] = X;
                    S[nxt][tid + 256 * j] = X;
                }
                if (tid == 0) {
                    float s, c;
                    __sincosf(nyph, &s, &c);
                    S[nxt][1024] = make_float2(nymg * c, 0.0f);
                }
            }
            __syncthreads();
        }
        // data now in W2

        // ---- P5: s4 (w=1) + fftshift + window -> register OLA; flush ----
        {
            float2 x0 = W2[pidx(tid)];
            float2 x1 = W2[pidx(tid + 256)];
            float2 x2 = W2[pidx(tid + 512)];
            float2 x3 = W2[pidx(tid + 768)];
            float2 u0 = make_float2(x0.x + x2.x, x0.y + x2.y);
            float2 u1 = make_float2(x0.x - x2.x, x0.y - x2.y);
            float2 u2 = make_float2(x1.x + x3.x, x1.y + x3.y);
            float2 u3 = make_float2(-(x1.y - x3.y), x1.x - x3.x);   // i*(x1-x3)
            float2 y;
            // n=tid+512 -> t2=tid   -> chunk fi,   window r0
            y = make_float2(u0.x - u2.x, u0.y - u2.y);
            acc[fi & 3].x += y.x * r0.x;  acc[fi & 3].y += y.y * r0.y;
            // n=tid+768 -> t2=tid+256 -> chunk fi+1, window r1
            y = make_float2(u1.x - u3.x, u1.y - u3.y);
            acc[(fi + 1) & 3].x += y.x * r1.x;  acc[(fi + 1) & 3].y += y.y * r1.y;
            // n=tid     -> t2=tid+512 -> chunk fi+2, window r2
            y = make_float2(u0.x + u2.x, u0.y + u2.y);
            acc[(fi + 2) & 3].x += y.x * r2.x;  acc[(fi + 2) & 3].y += y.y * r2.y;
            // n=tid+256 -> t2=tid+768 -> chunk fi+3, window r3
            y = make_float2(u1.x + u3.x, u1.y + u3.y);
            acc[(fi + 3) & 3].x += y.x * r3.x;  acc[(fi + 3) & 3].y += y.y * r3.y;

            // flush chunk fi (complete), re-zero slot for chunk fi+4
            float2 v = acc[fi & 3];
            acc[fi & 3] = make_float2(0.0f, 0.0f);
            long p = (long)(frame0 + fi) * HOP + 2 * tid - 1536;
            if (fi >= 3) {                           // interior: plain store
                if (p >= 0 && p < out_size)         out[p]     = v.x;
                if (p + 1 >= 0 && p + 1 < out_size) out[p + 1] = v.y;
            } else {                                 // seam: atomic
                if (p >= 0 && p < out_size)         atomicAdd(out + p,     v.x);
                if (p + 1 >= 0 && p + 1 < out_size) atomicAdd(out + p + 1, v.y);
            }
        }
        // no barrier: next write to W2 (P2 of fi+1) is 2 barriers away
    }

    // ---- tail: chunks 8,9,10 partial -> atomic ----
    #pragma unroll
    for (int lc = 8; lc <= 10; ++lc) {
        float2 v = acc[lc & 3];
        long p = (long)(frame0 + lc) * HOP + 2 * tid - 1536;
        if (p >= 0 && p < out_size)         atomicAdd(out + p,     v.x);
        if (p + 1 >= 0 && p + 1 < out_size) atomicAdd(out + p + 1, v.y);
    }
}

extern "C" void kernel_launch(void* const* d_in, const int* in_sizes, int n_in,
                              void* d_out, int out_size, void* d_ws, size_t ws_size,
                              hipStream_t stream) {
    const float* mag = (const float*)d_in[0];
    const float* ph  = (const float*)d_in[1];
    float* out = (float*)d_out;
    float* rs  = (float*)d_ws;

    hipMemsetAsync(d_out, 0, (size_t)out_size * sizeof(float), stream);
    init_rs_kernel<<<(WIN + 255) / 256, 256, 0, stream>>>(rs);
    istft_kernel<<<NFRAMES / FPB, 256, 0, stream>>>(mag, ph, rs, out, out_size);
}

// Round 11
// 58.224 us; speedup vs baseline: 4.5898x; 1.1904x over previous
//
#include <hip/hip_runtime.h>

#define WIN      2048
#define HOP      512
#define NFRAMES  16384
#define NBINS    1025      // WIN/2 + 1
#define FPB      16        // frames (= output chunks) per block

__device__ __forceinline__ int pidx(int a) { return a + (a >> 3); }
__device__ __forceinline__ float2 cmul(float2 a, float2 b) {
    return make_float2(a.x * b.x - a.y * b.y, a.x * b.y + a.y * b.x);
}

// ---------------------------------------------------------------------------
// 256 threads, 16 frames, software pipeline (4 barriers/frame):
//  P1: issue frame fi+1 global loads (regs); pack fi (Xk from regs, mirror
//      from Scur) fused with radix-4 stage0 -> W1             [barrier]
//  P2: s1  W1 -> W2                                           [barrier]
//  P3: s2  W2 -> W1                                           [barrier]
//  P4: s3  W1 -> W2 ; sincos(fi+1) -> xkB regs + Snxt         [barrier]
//  P5: s4 (twiddle=1) + fftshift + window -> acc0..acc3 register OLA
//      (thread owns intra-chunk offset 2*tid); flush chunk fi (acc0) to
//      global (plain interior / atomic seams); rotate acc, copy xkB->xkA,
//      swap Scur/Snxt. No barrier (next W-buffer write is 2 barriers away).
// Synthesis window rs computed in-kernel (env positions == needed positions
// since 2*tid < 512 -> no wrap); no init kernel, d_ws unused.
// ---------------------------------------------------------------------------
__global__ __launch_bounds__(256, 4) void istft_kernel(
        const float* __restrict__ mag, const float* __restrict__ ph,
        float* __restrict__ out, int out_size) {
    __shared__ float2 W1[1152];          // 9216 B (pidx-padded 1024)
    __shared__ float2 W2[1152];          // 9216 B
    __shared__ float2 S0[1026], S1[1026];// 2 x 8208 B spectrum buffers

    const int tid    = threadIdx.x;
    const int frame0 = blockIdx.x * FPB;

    // ---- frame-invariant per-thread constants ----
    float2 wpk;                                    // e^{2pi i tid/2048}
    sincospif((float)tid * (1.0f / 1024.0f), &wpk.y, &wpk.x);
    float2 wst[4], w2st[4];
    wst[0] = cmul(wpk, wpk);                       // e^{2pi i tid/1024}
    sincospif((float)(tid & ~3)  * (1.0f / 512.0f), &wst[1].y, &wst[1].x);
    sincospif((float)(tid & ~15) * (1.0f / 512.0f), &wst[2].y, &wst[2].x);
    sincospif((float)(tid & ~63) * (1.0f / 512.0f), &wst[3].y, &wst[3].x);
    #pragma unroll
    for (int q = 0; q < 4; ++q) w2st[q] = cmul(wst[q], wst[q]);

    // synthesis window (matches _gl_alg(2048,512,4094) folded with 1/1024):
    // rq[w] = {rs[2*tid+512w], rs[2*tid+1+512w]}
    float2 rq[4];
    {
        const float inv2047 = 1.0f / 2047.0f;
        const float scale   = rsqrtf(4094.0f);
        float he[4], ho[4];
        float envE = 0.0f, envO = 0.0f;
        #pragma unroll
        for (int w = 0; w < 4; ++w) {
            he[w] = (0.54f - 0.46f * cospif((float)(2 * tid     + 512 * w) * 2.0f * inv2047)) * scale;
            ho[w] = (0.54f - 0.46f * cospif((float)(2 * tid + 1 + 512 * w) * 2.0f * inv2047)) * scale;
            envE += he[w] * he[w];
            envO += ho[w] * ho[w];
        }
        const float se = 1.0f / (envE * 1024.0f);
        const float so = 1.0f / (envO * 1024.0f);
        #pragma unroll
        for (int w = 0; w < 4; ++w) rq[w] = make_float2(he[w] * se, ho[w] * so);
    }
    const float2 r0 = rq[0], r1 = rq[1], r2 = rq[2], r3 = rq[3];
    const float RT = 0.70710678118654752f;         // sqrt(2)/2

    float2 xkA0, xkA1, xkA2, xkA3;       // forward bins, current frame
    float2 xkB0, xkB1, xkB2, xkB3;       // forward bins, next frame
    float  mgn[4], ppn[4], nymg, nyph;   // staged loads for next frame
    float2 acc0, acc1, acc2, acc3;       // live OLA chunks fi..fi+3 @ 2*tid
    acc0 = acc1 = acc2 = acc3 = make_float2(0.0f, 0.0f);
    float2* Scur = S0;
    float2* Snxt = S1;

    // ---- prologue: load + convert frame 0, write Scur ----
    {
        const float* magf = mag + (size_t)frame0 * NBINS;
        const float* phf  = ph  + (size_t)frame0 * NBINS;
        #pragma unroll
        for (int j = 0; j < 4; ++j) {
            mgn[j] = magf[tid + 256 * j];
            ppn[j] = phf[tid + 256 * j];
        }
        nymg = magf[1024]; nyph = phf[1024];
        float2 X[4];
        #pragma unroll
        for (int j = 0; j < 4; ++j) {
            float s, c;
            __sincosf(ppn[j], &s, &c);
            X[j] = make_float2(mgn[j] * c, mgn[j] * s);
            if (j == 0 && tid == 0) X[j].y = 0.0f;     // DC imag
            Scur[tid + 256 * j] = X[j];
        }
        xkA0 = X[0]; xkA1 = X[1]; xkA2 = X[2]; xkA3 = X[3];
        if (tid == 0) {
            float s, c;
            __sincosf(nyph, &s, &c);
            Scur[1024] = make_float2(nymg * c, 0.0f);  // Nyquist imag = 0
        }
    }
    __syncthreads();

    for (int fi = 0; fi < FPB; ++fi) {
        // ---- P1: issue next-frame loads, then pack + s0 -> W1 ----
        if (fi < FPB - 1) {
            const float* magf = mag + (size_t)(frame0 + fi + 1) * NBINS;
            const float* phf  = ph  + (size_t)(frame0 + fi + 1) * NBINS;
            #pragma unroll
            for (int j = 0; j < 4; ++j) {
                mgn[j] = magf[tid + 256 * j];
                ppn[j] = phf[tid + 256 * j];
            }
            nymg = magf[1024]; nyph = phf[1024];
        }
        {
            float2 z[4];
            #pragma unroll
            for (int j = 0; j < 4; ++j) {
                float2 Xk = (j == 0) ? xkA0 : (j == 1) ? xkA1 : (j == 2) ? xkA2 : xkA3;
                float2 Xm = Scur[1024 - (tid + 256 * j)];
                float2 wj;                         // wpk * e^{i pi j/4}
                if      (j == 0) wj = wpk;
                else if (j == 1) wj = make_float2(RT * (wpk.x - wpk.y), RT * (wpk.x + wpk.y));
                else if (j == 2) wj = make_float2(-wpk.y, wpk.x);
                else             wj = make_float2(-RT * (wpk.x + wpk.y), RT * (wpk.x - wpk.y));
                float Er = 0.5f * (Xk.x + Xm.x), Ei = 0.5f * (Xk.y - Xm.y);
                float Tr = Xm.x - Xk.x,          Ti = -Xm.y - Xk.y;
                float Or = 0.5f * (wj.x * Ti + wj.y * Tr);
                float Oi = 0.5f * (wj.y * Ti - wj.x * Tr);
                z[j] = make_float2(Er + Or, Ei + Oi);
            }
            float2 w = wst[0], w2 = w2st[0];
            float2 u0 = make_float2(z[0].x + z[2].x, z[0].y + z[2].y);
            float  ar = z[0].x - z[2].x, ai = z[0].y - z[2].y;
            float2 u1 = make_float2(ar * w.x - ai * w.y, ar * w.y + ai * w.x);
            float2 u2 = make_float2(z[1].x + z[3].x, z[1].y + z[3].y);
            float  br = z[1].x - z[3].x, bi = z[1].y - z[3].y;
            float2 u3 = make_float2(-br * w.y - bi * w.x, br * w.x - bi * w.y);
            const int base = 4 * tid;              // tid + 3*G, G=tid, s4=1
            W1[pidx(base)]     = make_float2(u0.x + u2.x, u0.y + u2.y);
            W1[pidx(base + 1)] = make_float2(u1.x + u3.x, u1.y + u3.y);
            float dr = u0.x - u2.x, di = u0.y - u2.y;
            W1[pidx(base + 2)] = make_float2(dr * w2.x - di * w2.y, dr * w2.y + di * w2.x);
            float er = u1.x - u3.x, ei = u1.y - u3.y;
            W1[pidx(base + 3)] = make_float2(er * w2.x - ei * w2.y, er * w2.y + ei * w2.x);
        }
        __syncthreads();

        // ---- P2/P3/P4: stages 1..3 ----
        #pragma unroll
        for (int st = 1; st < 4; ++st) {
            float2* src = (st == 2) ? W2 : W1;     // s1:W1->W2 s2:W2->W1 s3:W1->W2
            float2* dst = (st == 2) ? W1 : W2;
            const int s4 = 1 << (2 * st);
            const int G  = tid & ~(s4 - 1);
            const float2 w = wst[st], w2 = w2st[st];
            float2 x0 = src[pidx(tid)];
            float2 x1 = src[pidx(tid + 256)];
            float2 x2 = src[pidx(tid + 512)];
            float2 x3 = src[pidx(tid + 768)];
            float2 u0 = make_float2(x0.x + x2.x, x0.y + x2.y);
            float  ar = x0.x - x2.x, ai = x0.y - x2.y;
            float2 u1 = make_float2(ar * w.x - ai * w.y, ar * w.y + ai * w.x);
            float2 u2 = make_float2(x1.x + x3.x, x1.y + x3.y);
            float  br = x1.x - x3.x, bi = x1.y - x3.y;
            float2 u3 = make_float2(-br * w.y - bi * w.x, br * w.x - bi * w.y);
            const int base = tid + 3 * G;
            dst[pidx(base)]          = make_float2(u0.x + u2.x, u0.y + u2.y);
            dst[pidx(base + s4)]     = make_float2(u1.x + u3.x, u1.y + u3.y);
            float dr = u0.x - u2.x, di = u0.y - u2.y;
            dst[pidx(base + 2 * s4)] = make_float2(dr * w2.x - di * w2.y, dr * w2.y + di * w2.x);
            float er = u1.x - u3.x, ei = u1.y - u3.y;
            dst[pidx(base + 3 * s4)] = make_float2(er * w2.x - ei * w2.y, er * w2.y + ei * w2.x);

            // fold next-frame spectrum conversion into the s3 phase
            if (st == 3 && fi < FPB - 1) {
                float2 X[4];
                #pragma unroll
                for (int j = 0; j < 4; ++j) {
                    float s, c;
                    __sincosf(ppn[j], &s, &c);
                    X[j] = make_float2(mgn[j] * c, mgn[j] * s);
                    if (j == 0 && tid == 0) X[j].y = 0.0f;
                    Snxt[tid + 256 * j] = X[j];
                }
                xkB0 = X[0]; xkB1 = X[1]; xkB2 = X[2]; xkB3 = X[3];
                if (tid == 0) {
                    float s, c;
                    __sincosf(nyph, &s, &c);
                    Snxt[1024] = make_float2(nymg * c, 0.0f);
                }
            }
            __syncthreads();
        }
        // data now in W2

        // ---- P5: s4 (w=1) + fftshift + window -> register OLA; flush ----
        {
            float2 x0 = W2[pidx(tid)];
            float2 x1 = W2[pidx(tid + 256)];
            float2 x2 = W2[pidx(tid + 512)];
            float2 x3 = W2[pidx(tid + 768)];
            float2 u0 = make_float2(x0.x + x2.x, x0.y + x2.y);
            float2 u1 = make_float2(x0.x - x2.x, x0.y - x2.y);
            float2 u2 = make_float2(x1.x + x3.x, x1.y + x3.y);
            float2 u3 = make_float2(-(x1.y - x3.y), x1.x - x3.x);   // i*(x1-x3)
            float2 y;
            // n=tid+512 -> t2=tid     -> chunk fi   (acc0), window r0
            y = make_float2(u0.x - u2.x, u0.y - u2.y);
            acc0.x += y.x * r0.x;  acc0.y += y.y * r0.y;
            // n=tid+768 -> t2=tid+256 -> chunk fi+1 (acc1), window r1
            y = make_float2(u1.x - u3.x, u1.y - u3.y);
            acc1.x += y.x * r1.x;  acc1.y += y.y * r1.y;
            // n=tid     -> t2=tid+512 -> chunk fi+2 (acc2), window r2
            y = make_float2(u0.x + u2.x, u0.y + u2.y);
            acc2.x += y.x * r2.x;  acc2.y += y.y * r2.y;
            // n=tid+256 -> t2=tid+768 -> chunk fi+3 (acc3), window r3
            y = make_float2(u1.x + u3.x, u1.y + u3.y);
            acc3.x += y.x * r3.x;  acc3.y += y.y * r3.y;

            // flush chunk fi (complete)
            float2 v = acc0;
            long p = (long)(frame0 + fi) * HOP + 2 * tid - 1536;
            if (fi >= 3) {                           // interior: plain store
                if (p >= 0 && p < out_size)         out[p]     = v.x;
                if (p + 1 >= 0 && p + 1 < out_size) out[p + 1] = v.y;
            } else {                                 // seam: atomic
                if (p >= 0 && p < out_size)         atomicAdd(out + p,     v.x);
                if (p + 1 >= 0 && p + 1 < out_size) atomicAdd(out + p + 1, v.y);
            }
            // rotate state for next slot
            acc0 = acc1; acc1 = acc2; acc2 = acc3;
            acc3 = make_float2(0.0f, 0.0f);
            xkA0 = xkB0; xkA1 = xkB1; xkA2 = xkB2; xkA3 = xkB3;
            float2* tmp = Scur; Scur = Snxt; Snxt = tmp;
        }
        // no barrier: next write to W-buffers is 2 barriers away
    }

    // ---- tail: chunks FPB..FPB+2 partial -> atomic ----
    #pragma unroll
    for (int e = 0; e < 3; ++e) {
        float2 v = (e == 0) ? acc0 : (e == 1) ? acc1 : acc2;
        long p = (long)(frame0 + FPB + e) * HOP + 2 * tid - 1536;
        if (p >= 0 && p < out_size)         atomicAdd(out + p,     v.x);
        if (p + 1 >= 0 && p + 1 < out_size) atomicAdd(out + p + 1, v.y);
    }
}

extern "C" void kernel_launch(void* const* d_in, const int* in_sizes, int n_in,
                              void* d_out, int out_size, void* d_ws, size_t ws_size,
                              hipStream_t stream) {
    const float* mag = (const float*)d_in[0];
    const float* ph  = (const float*)d_in[1];
    float* out = (float*)d_out;

    hipMemsetAsync(d_out, 0, (size_t)out_size * sizeof(float), stream);
    istft_kernel<<<NFRAMES / FPB, 256, 0, stream>>>(mag, ph, out, out_size);
}